// Round 1
// baseline (209.211 us; speedup 1.0000x reference)
//
#include <hip/hip_runtime.h>
#include <hip/hip_bf16.h>

// Problem: B=8192 rows, F=4096 features, K=64 factors.
// out[b] = 0.5 * ( ||x_b @ v||^2  -  (x_b^2) . w ),  w[f] = sum_k v[f][k]^2

#define F_DIM 4096
#define K_DIM 64
#define B_ROWS 8192

typedef __attribute__((ext_vector_type(8))) short short8;
typedef __attribute__((ext_vector_type(4))) float float4v;

__device__ __forceinline__ short f2bs(float f) {
    __hip_bfloat16 h = __float2bfloat16(f);
    short s;
    __builtin_memcpy(&s, &h, 2);
    return s;
}

// Prep: vt[n][f] = bf16(v[f][n]); w[f] = sum_n v[f][n]^2
__global__ void prep_kernel(const float* __restrict__ v,
                            __hip_bfloat16* __restrict__ vt,
                            float* __restrict__ w) {
    const int wave = (blockIdx.x * blockDim.x + threadIdx.x) >> 6;
    const int lane = threadIdx.x & 63;
    if (wave >= F_DIM) return;
    const float val = v[wave * K_DIM + lane];
    float sq = val * val;
#pragma unroll
    for (int m = 32; m >= 1; m >>= 1) sq += __shfl_xor(sq, m, 64);
    if (lane == 0) w[wave] = sq;
    vt[(size_t)lane * F_DIM + wave] = __float2bfloat16(val);
}

// Main: block = 16 rows, 8 waves split f-dim 8-ways (512 f each).
// A-fragments loaded straight from global fp32 in MFMA layout, cvt to bf16.
__launch_bounds__(512, 4)
__global__ void fm_main_kernel(const float* __restrict__ x,
                               const __hip_bfloat16* __restrict__ vt,
                               const float* __restrict__ w,
                               float* __restrict__ out) {
    __shared__ float yred[8][16][64];  // 32 KB: per-wave partial y
    __shared__ float s2s[16];
    __shared__ float s1s[16];

    const int tid  = threadIdx.x;
    const int lane = tid & 63;
    const int wid  = tid >> 6;
    const int lrow = lane & 15;          // MFMA A row / B col
    const int lk8  = (lane >> 4) * 8;    // MFMA k offset (8 contiguous)
    const int row0 = blockIdx.x * 16;

    if (tid < 16) s2s[tid] = 0.0f;
    __syncthreads();

    const float* xrow = x + (size_t)(row0 + lrow) * F_DIM;

    float4v acc0 = {0.f,0.f,0.f,0.f}, acc1 = {0.f,0.f,0.f,0.f};
    float4v acc2 = {0.f,0.f,0.f,0.f}, acc3 = {0.f,0.f,0.f,0.f};
    float s2p = 0.0f;

    const int fbase = wid * (F_DIM / 8);   // 512 f per wave

#pragma unroll 4
    for (int ks = 0; ks < (F_DIM / 8) / 32; ++ks) {   // 16 k-steps of 32
        const int fo = fbase + ks * 32 + lk8;
        const float4v xa = *(const float4v*)(xrow + fo);
        const float4v xb = *(const float4v*)(xrow + fo + 4);
        const float4v wa = *(const float4v*)(w + fo);
        const float4v wb = *(const float4v*)(w + fo + 4);

        s2p += xa.x*xa.x*wa.x + xa.y*xa.y*wa.y + xa.z*xa.z*wa.z + xa.w*xa.w*wa.w
             + xb.x*xb.x*wb.x + xb.y*xb.y*wb.y + xb.z*xb.z*wb.z + xb.w*xb.w*wb.w;

        short8 af;
        af[0]=f2bs(xa.x); af[1]=f2bs(xa.y); af[2]=f2bs(xa.z); af[3]=f2bs(xa.w);
        af[4]=f2bs(xb.x); af[5]=f2bs(xb.y); af[6]=f2bs(xb.z); af[7]=f2bs(xb.w);

        const __hip_bfloat16* bbase = vt + (size_t)lrow * F_DIM + fo;
        const short8 b0 = *(const short8*)(bbase);
        const short8 b1 = *(const short8*)(bbase + 16 * F_DIM);
        const short8 b2 = *(const short8*)(bbase + 32 * F_DIM);
        const short8 b3 = *(const short8*)(bbase + 48 * F_DIM);

        acc0 = __builtin_amdgcn_mfma_f32_16x16x32_bf16(af, b0, acc0, 0, 0, 0);
        acc1 = __builtin_amdgcn_mfma_f32_16x16x32_bf16(af, b1, acc1, 0, 0, 0);
        acc2 = __builtin_amdgcn_mfma_f32_16x16x32_bf16(af, b2, acc2, 0, 0, 0);
        acc3 = __builtin_amdgcn_mfma_f32_16x16x32_bf16(af, b3, acc3, 0, 0, 0);
    }

    // s2: lanes {l, l+16, l+32, l+48} cover disjoint k-slices of row lrow
    s2p += __shfl_xor(s2p, 16, 64);
    s2p += __shfl_xor(s2p, 32, 64);
    if (lane < 16) atomicAdd(&s2s[lrow], s2p);

    // dump per-wave y partials: D row = (lane>>4)*4 + r, col = cg*16 + (lane&15)
    const int arow = (lane >> 4) * 4;
#pragma unroll
    for (int r = 0; r < 4; ++r) {
        yred[wid][arow + r][ 0 + lrow] = acc0[r];
        yred[wid][arow + r][16 + lrow] = acc1[r];
        yred[wid][arow + r][32 + lrow] = acc2[r];
        yred[wid][arow + r][48 + lrow] = acc3[r];
    }
    __syncthreads();

    // s1: wave `wid` reduces rows {wid, wid+8}; lane = column
#pragma unroll
    for (int half = 0; half < 2; ++half) {
        const int row = wid + half * 8;
        float y = 0.0f;
#pragma unroll
        for (int wv = 0; wv < 8; ++wv) y += yred[wv][row][lane];
        float yy = y * y;
#pragma unroll
        for (int m = 32; m >= 1; m >>= 1) yy += __shfl_xor(yy, m, 64);
        if (lane == 0) s1s[row] = yy;
    }
    __syncthreads();

    if (tid < 16) out[row0 + tid] = 0.5f * (s1s[tid] - s2s[tid]);
}

extern "C" void kernel_launch(void* const* d_in, const int* in_sizes, int n_in,
                              void* d_out, int out_size, void* d_ws, size_t ws_size,
                              hipStream_t stream) {
    const float* x = (const float*)d_in[0];   // [8192, 4096] fp32
    const float* v = (const float*)d_in[1];   // [4096, 64]   fp32
    float* out = (float*)d_out;               // [8192]       fp32

    __hip_bfloat16* vt = (__hip_bfloat16*)d_ws;                 // 64*4096*2 = 512 KB
    float* w = (float*)((char*)d_ws + (size_t)K_DIM * F_DIM * 2); // 16 KB

    // prep: one wave per f-row
    prep_kernel<<<F_DIM / 4, 256, 0, stream>>>(v, vt, w);

    // main: 512 blocks x 512 threads, 16 rows per block
    fm_main_kernel<<<B_ROWS / 16, 512, 0, stream>>>(x, vt, w, out);
}